// Round 4
// baseline (126.915 us; speedup 1.0000x reference)
//
#include <hip/hip_runtime.h>
#include <math.h>

// Problem constants (B=8, H=W=32, D=256, heads=4, hd=64)
#define NTOK   1024
#define DMODEL 256
#define NHEADS 4
#define HDIM   64
#define NROWS  8192
#define LOG2E  1.4426950408889634f

typedef __attribute__((ext_vector_type(8))) short          bf16x8;
typedef __attribute__((ext_vector_type(8))) unsigned short ushort8;
typedef __attribute__((ext_vector_type(4))) unsigned short ushort4v;
typedef __attribute__((ext_vector_type(4))) float          f32x4;
typedef __attribute__((ext_vector_type(4))) unsigned int   u32x4;

union ABits { u32x4 u; bf16x8 b; };

__device__ __forceinline__ unsigned short f2bf(float x) {   // RNE fp32->bf16
    unsigned u = __float_as_uint(x);
    u = (u + 0x7fffu + ((u >> 16) & 1u)) >> 16;
    return (unsigned short)u;
}
__device__ __forceinline__ float bf2f(unsigned short u) {
    return __uint_as_float(((unsigned)u) << 16);
}
// pack two fp32 -> two bf16 (truncating) in ONE v_perm_b32 (P values only)
__device__ __forceinline__ unsigned pk_bf2(float lo, float hi) {
    return __builtin_amdgcn_perm(__float_as_uint(hi), __float_as_uint(lo),
                                 0x07060302u);
}
// RNE packed fp32->bf16 pair: 1 instruction for 2 elements (gfx950)
__device__ __forceinline__ unsigned cvt2(float lo, float hi) {
    unsigned r;
    asm("v_cvt_pk_bf16_f32 %0, %1, %2" : "=v"(r) : "v"(lo), "v"(hi));
    return r;
}

// async global->LDS DMA, 16 B per lane; LDS dest = wave-uniform base + lane*16
#define GLD_LDS16(gp, lp)                                            \
    __builtin_amdgcn_global_load_lds(                                \
        (__attribute__((address_space(1))) void*)(gp),               \
        (__attribute__((address_space(3))) void*)(lp), 16, 0, 0)

// ---------------------------------------------------------------------------
// Kernel 1: QK projection GEMM with ALL prep folded into the same 512 blocks.
//  - 64x64 QK tile per block; A cast fp32->bf16 inline (cvt_pk); Wq/Wk tiles
//    reg-staged fp32->bf16 into swizzled LDS.
//  - Each block ALSO transposes the head-h (h = n0/64) slice of its own 64
//    token rows into Vt.  Bias expansion rides on blocks 0..239.
//  Grid 512 = exactly one round at 2 blocks/CU (74 KB LDS).
// ---------------------------------------------------------------------------
__global__ __launch_bounds__(256, 2) void fused_prep_qk(
    const float* __restrict__ X,
    const float* __restrict__ Wq, const float* __restrict__ bq,
    const float* __restrict__ Wk, const float* __restrict__ bk,
    const float* __restrict__ bt,
    unsigned short* __restrict__ Qb, unsigned short* __restrict__ Kb,
    unsigned short* __restrict__ Vt, float* __restrict__ Pb3)
{
    __shared__ unsigned short Bs[2][64 * 256];   // 64 KB weight tiles
    __shared__ unsigned short T[64][80];         // 10 KB V-transpose buffer

    const int bid = blockIdx.x;                  // 0..511
    const int t   = threadIdx.x;
    const int n0  = (bid & 3) * 64;
    const int m0  = (bid >> 2) * 64;
    const int h   = bid & 3;                     // head whose Vt slice we own
    const int b   = bid >> 6;                    // batch of our token rows
    const int kt  = (bid >> 2) & 15;             // 64-token chunk inside batch
    const int bh  = b * NHEADS + h;
    const int wv = t >> 6, lane = t & 63;
    const int quad = lane >> 4, l16 = lane & 15;

    // ---- fused bias expansion (61440 elems across blocks 0..239) ----
    const int gid = bid * 256 + t;
    if (gid < NHEADS * 15 * 1024) {
        const int w2 = gid & 31;
        const int w1 = (gid >> 5) & 31;
        const int rh = (gid >> 10) % 15;
        const int hh = gid / (15 * 1024);
        int rw = w1 - w2 + 7; rw = rw < 0 ? 0 : (rw > 14 ? 14 : rw);
        Pb3[gid] = bt[(rh * 15 + rw) * NHEADS + hh] * LOG2E;
    }

    // ---- stage Wq/Wk 64x256 tiles: fp32 read, cvt_pk cast, swizzled LDS ----
    #pragma unroll
    for (int i = 0; i < 16; i++) {
        const int gran = i * 256 + t;          // 0..4095
        const int mtx  = gran >> 11;           // 0=Wq 1=Wk (uniform per i)
        const int rem  = gran & 2047;
        const int n    = rem >> 5;             // row 0..63
        const int g    = rem & 31;             // K-granule 0..31
        const float* __restrict__ Ws = mtx ? Wk : Wq;
        const float4 f0 = *(const float4*)&Ws[(n0 + n)*DMODEL + g*8];
        const float4 f1 = *(const float4*)&Ws[(n0 + n)*DMODEL + g*8 + 4];
        u32x4 wpk;
        wpk[0] = cvt2(f0.x, f0.y); wpk[1] = cvt2(f0.z, f0.w);
        wpk[2] = cvt2(f1.x, f1.y); wpk[3] = cvt2(f1.z, f1.w);
        *(u32x4*)&Bs[mtx][n*256 + 8*(g ^ (n & 7))] = wpk;
    }

    // ---- V-transpose phase 1: head-h slice of our 64 rows -> T (cast) ----
    {
        const int key = t >> 2;                // 0..63
        const int d4  = (t & 3) * 16;          // 0,16,32,48
        const long roff = (long)(b*NTOK + kt*64 + key)*DMODEL + h*HDIM;
        #pragma unroll
        for (int j = 0; j < 4; j++) {
            const float4 v = *(const float4*)&X[roff + d4 + j*4];
            T[d4+j*4+0][key] = f2bf(v.x); T[d4+j*4+1][key] = f2bf(v.y);
            T[d4+j*4+2][key] = f2bf(v.z); T[d4+j*4+3][key] = f2bf(v.w);
        }
    }
    __syncthreads();

    // ---- V-transpose phase 2: T -> Vt coalesced (overlaps K-loop setup) ----
    #pragma unroll
    for (int i = 0; i < 2; i++) {
        const int tt = t + 256 * i;            // 0..511
        const int d  = tt >> 3;                // 0..63
        const int g  = tt & 7;                 // 0..7
        const ushort8 o = *(const ushort8*)&T[d][g*8];
        *(ushort8*)&Vt[(bh*HDIM + d)*NTOK + kt*64 + g*8] = o;
    }

    // ---- QK GEMM ----
    const int rowbase = m0 + wv * 16;

    f32x4 acc[2][4];
    #pragma unroll
    for (int nf = 0; nf < 4; nf++) {
        const float bvq = bq[n0 + nf*16 + l16];
        const float bvk = bk[n0 + nf*16 + l16];
        acc[0][nf] = (f32x4){bvq,bvq,bvq,bvq};
        acc[1][nf] = (f32x4){bvk,bvk,bvk,bvk};
    }

    const float* __restrict__ Arow = &X[(rowbase + l16) * DMODEL];

    for (int ks = 0; ks < 8; ks++) {
        const float4 x0 = *(const float4*)&Arow[ks*32 + quad*8];
        const float4 x1 = *(const float4*)&Arow[ks*32 + quad*8 + 4];
        ABits a;
        a.u[0] = cvt2(x0.x, x0.y); a.u[1] = cvt2(x0.z, x0.w);
        a.u[2] = cvt2(x1.x, x1.y); a.u[3] = cvt2(x1.z, x1.w);
        #pragma unroll
        for (int nf = 0; nf < 4; nf++) {
            const int n  = nf*16 + l16;
            const int so = n*256 + 8*((ks*4 + quad) ^ (n & 7));
            const bf16x8 bq8 = *(const bf16x8*)&Bs[0][so];
            const bf16x8 bk8 = *(const bf16x8*)&Bs[1][so];
            acc[0][nf] = __builtin_amdgcn_mfma_f32_16x16x32_bf16(a.b, bq8, acc[0][nf], 0, 0, 0);
            acc[1][nf] = __builtin_amdgcn_mfma_f32_16x16x32_bf16(a.b, bk8, acc[1][nf], 0, 0, 0);
        }
    }

    const float qscale = 0.125f * LOG2E;
    #pragma unroll
    for (int nf = 0; nf < 4; nf++) {
        const int col = n0 + nf*16 + l16;
        #pragma unroll
        for (int r = 0; r < 4; r++) {
            const int row = rowbase + quad*4 + r;
            Qb[row*DMODEL + col] = f2bf(acc[0][nf][r] * qscale);
            Kb[row*DMODEL + col] = f2bf(acc[1][nf][r]);
        }
    }
}

// ---------------------------------------------------------------------------
// Kernel 2: MFMA flash attention, split-K=2, 64-key chunks, Q-TILE = 256 rows.
// 1024 threads / 16 waves per block; each wave owns 16 q-rows (per-wave code
// identical to the 128-row version).  K/V staging per chunk (16 KB) amortized
// over 2x more MFMA work -> chip-wide K/V cache reads halve again (64->32 MB,
// vs 8 MB unique).  Stage = 1 GLD per wave (waves 0-7 K, waves 8-15 V).
// Grid (4 qt, 32 bh, 2 halves) = 256 blocks = 1 block/CU, 16 waves/CU.
// LDS 64 KB.  K,V double-buffered async-DMA; Ps XOR-swizzled; s_setprio.
// ---------------------------------------------------------------------------
__global__ __launch_bounds__(1024, 4) void attn_mfma(
    const unsigned short* __restrict__ Qb, const unsigned short* __restrict__ Kb,
    const unsigned short* __restrict__ Vt, const float* __restrict__ Pb3,
    unsigned short* __restrict__ Op, float* __restrict__ rsum)
{
    const int qt   = blockIdx.x;    // 0..3
    const int bh   = blockIdx.y;    // 0..31
    const int qr   = blockIdx.z;    // 0..1 (key half)
    const int b    = bh >> 2, h = bh & 3;
    const int t    = threadIdx.x;
    const int wv   = t >> 6, lane = t & 63;   // wv 0..15
    const int quad = lane >> 4, l16 = lane & 15;

    __shared__ unsigned short Ks[2][64 * 64];   // 16 KB
    __shared__ unsigned short Vs[2][64 * 64];   // 16 KB
    __shared__ unsigned short Ps[16][16 * 64];  // 32 KB, XOR-swizzled

    const int qbase = qt * 256 + wv * 16;
    const int h1    = qbase >> 5;               // wave-uniform
    const int w1    = (qbase & 31) + l16;

    bf16x8 qa0, qa1;
    {
        const unsigned short* qp =
            &Qb[(b*NTOK + qbase + l16) * DMODEL + h*HDIM + quad*8];
        qa0 = *(const bf16x8*)(qp);
        qa1 = *(const bf16x8*)(qp + 32);
    }

    f32x4 Of[4] = {};
    float rs = 0.f;

    const unsigned short* KbBase = &Kb[(b*NTOK) * DMODEL + h*HDIM];
    const unsigned short* VtBase = &Vt[(bh*HDIM) * NTOK];
    unsigned short* Pw = Ps[wv];
    const int cbase = qr * 512;

    // async-DMA a 64-key K+V chunk into buffer pb (swizzle via permuted column)
    // 16 waves -> ONE granule-row per wave: waves 0..7 stage K, 8..15 stage V.
    auto stage = [&](int c0, int pb) {
        if (wv < 8) {
            const int gr  = wv*64 + lane;           // 0..511
            const int key = gr >> 3, gs = gr & 7;
            const int g   = gs ^ (key & 7);
            GLD_LDS16(&KbBase[(c0 + key)*DMODEL + g*8], &Ks[pb][(wv*64)*8]);
        } else {
            const int gr = (wv - 8)*64 + lane;      // 0..511
            const int d  = gr >> 3, gs = gr & 7;
            const int gk = gs ^ (d & 7);
            GLD_LDS16(&VtBase[d*NTOK + c0 + gk*8], &Vs[pb][((wv - 8)*64)*8]);
        }
    };

    stage(cbase, 0);
    __syncthreads();          // drains vmcnt -> chunk 0 resident

    for (int ch = 0; ch < 8; ch++) {
        const int c0 = cbase + ch * 64;
        const int p  = ch & 1;

        // async DMA for chunk ch+1 into the back buffer
        if (ch < 7) stage(c0 + 64, p ^ 1);

        // issue the 4 bias loads for this chunk up-front
        f32x4 bias_c[4];
        #pragma unroll
        for (int nt = 0; nt < 4; nt++) {
            const int nk = c0 + nt*16;
            const int h2 = nk >> 5;
            int rh = h1 - h2 + 7; rh = rh < 0 ? 0 : (rh > 14 ? 14 : rh);
            bias_c[nt] = *(const f32x4*)
                &Pb3[(((h*15 + rh)*32) + w1)*32 + (nk & 31) + quad*4];
        }

        // ---- scores: S^T tile = K_tile @ Q^T, bias preloaded in acc ----
        #pragma unroll
        for (int nt = 0; nt < 4; nt++) {
            f32x4 c = bias_c[nt];
            const int kk = nt*16 + l16;
            const bf16x8 ka0 = *(const bf16x8*)&Ks[p][kk*64 + 8*(quad ^ (kk & 7))];
            const bf16x8 ka1 = *(const bf16x8*)&Ks[p][kk*64 + 8*((quad+4) ^ (kk & 7))];
            __builtin_amdgcn_s_setprio(1);
            c = __builtin_amdgcn_mfma_f32_16x16x32_bf16(ka0, qa0, c, 0, 0, 0);
            c = __builtin_amdgcn_mfma_f32_16x16x32_bf16(ka1, qa1, c, 0, 0, 0);
            __builtin_amdgcn_s_setprio(0);
            const float p0 = exp2f(c[0]), p1 = exp2f(c[1]);
            const float p2 = exp2f(c[2]), p3 = exp2f(c[3]);
            rs += (p0 + p1) + (p2 + p3);
            uint2 pk;
            pk.x = pk_bf2(p0, p1);     // truncating bf16 pair-pack (1 instr)
            pk.y = pk_bf2(p2, p3);
            // P store: row=qrow=l16, keys nt*16+quad*4..+3 (swizzled granule)
            const int g = nt*2 + (quad >> 1);
            *(uint2*)&Pw[l16*64 + 8*(g ^ (l16 & 7)) + (quad & 1)*4] = pk;
        }
        // same-wave P write->read: DS pipe is in-order per wave; pin ordering
        __builtin_amdgcn_wave_barrier();

        // ---- PV: O += P V ----
        __builtin_amdgcn_s_setprio(1);
        #pragma unroll
        for (int ks = 0; ks < 2; ks++) {
            const bf16x8 pa = *(const bf16x8*)&Pw[l16*64 + 8*((ks*4 + quad) ^ (l16 & 7))];
            #pragma unroll
            for (int dt = 0; dt < 4; dt++) {
                const int dcol = dt*16 + l16;
                const bf16x8 vb = *(const bf16x8*)
                    &Vs[p][dcol*64 + 8*((ks*4 + quad) ^ (dcol & 7))];
                Of[dt] = __builtin_amdgcn_mfma_f32_16x16x32_bf16(pa, vb, Of[dt], 0, 0, 0);
            }
        }
        __builtin_amdgcn_s_setprio(0);

        // all waves done with buf p; ch+1 DMA drained (vmcnt(0) before barrier)
        if (ch < 7) __syncthreads();
    }

    // ---- epilogue: partial row sums + unnormalized bf16 partial O ----
    float tot = rs;
    tot += __shfl_xor(tot, 16);
    tot += __shfl_xor(tot, 32);          // full half-sum for q-row l16
    if (quad == 0)
        rsum[(qr*32 + bh)*NTOK + qbase + l16] = tot;

    #pragma unroll
    for (int dt = 0; dt < 4; dt++)
        #pragma unroll
        for (int r = 0; r < 4; r++) {
            const int row = qbase + quad*4 + r;
            Op[((long)qr*NROWS + b*NTOK + row)*DMODEL + h*HDIM + dt*16 + l16]
                = f2bf(Of[dt][r]);
        }
}

// ---------------------------------------------------------------------------
// Kernel 3: MFMA output projection + gated blend with FUSED 2-way split-K
// combine: A-frag = (Op0+Op1) * rinv[head] built in-register.
// Wo tile cast fp32->bf16 inline (reg-staged, swizzled LDS) — no Wob buffer.
// out = x + (1-g)*pe + g*(O @ Wo^T + bo), fp32 out.  64x64 tile, 512 blocks.
// ---------------------------------------------------------------------------
__global__ __launch_bounds__(256, 2) void gemm_out_mfma(
    const unsigned short* __restrict__ Op, const float* __restrict__ rsum,
    const float* __restrict__ Wo, const float* __restrict__ bo,
    const float* __restrict__ X, const float* __restrict__ PE,
    const float* __restrict__ gatep,
    float* __restrict__ Out)
{
    const int n0 = blockIdx.x * 64;
    const int m0 = blockIdx.y * 64;
    const int t  = threadIdx.x;
    const int wv = t >> 6, lane = t & 63;
    const int quad = lane >> 4, l16 = lane & 15;

    __shared__ unsigned short Bs[64 * 256];

    #pragma unroll
    for (int i = 0; i < 8; i++) {
        const int gran = i * 256 + t;          // 0..2047
        const int n    = gran >> 5;            // row 0..63
        const int g    = gran & 31;            // K-granule 0..31
        const float4 f0 = *(const float4*)&Wo[(n0 + n)*DMODEL + g*8];
        const float4 f1 = *(const float4*)&Wo[(n0 + n)*DMODEL + g*8 + 4];
        u32x4 wpk;
        wpk[0] = cvt2(f0.x, f0.y); wpk[1] = cvt2(f0.z, f0.w);
        wpk[2] = cvt2(f1.x, f1.y); wpk[3] = cvt2(f1.z, f1.w);
        *(u32x4*)&Bs[n*256 + 8*(g ^ (n & 7))] = wpk;
    }
    __syncthreads();

    const int rowbase = m0 + wv * 16;
    const int arow = rowbase + l16;          // this lane's A row
    const int ab = arow >> 10, an = arow & 1023;

    // per-head 1/(l0+l1) for this row
    float rinv4[4];
    #pragma unroll
    for (int hh = 0; hh < 4; hh++) {
        const float l0 = rsum[(      ab*NHEADS + hh)*NTOK + an];
        const float l1 = rsum[(32 +  ab*NHEADS + hh)*NTOK + an];
        rinv4[hh] = 1.0f / (l0 + l1);
    }

    f32x4 acc[4];
    #pragma unroll
    for (int nf = 0; nf < 4; nf++) {
        const float bv = bo[n0 + nf*16 + l16];
        acc[nf] = (f32x4){bv,bv,bv,bv};
    }

    for (int ks = 0; ks < 8; ks++) {
        const float ri = rinv4[ks >> 1];     // head = (ks*32)/64
        const long aoff = (long)arow*DMODEL + ks*32 + quad*8;
        const ushort8 p0 = *(const ushort8*)&Op[aoff];
        const ushort8 p1 = *(const ushort8*)&Op[(long)NROWS*DMODEL + aoff];
        ABits a;
        #pragma unroll
        for (int j = 0; j < 4; j++) {
            const float e0 = (bf2f(p0[2*j  ]) + bf2f(p1[2*j  ])) * ri;
            const float e1 = (bf2f(p0[2*j+1]) + bf2f(p1[2*j+1])) * ri;
            a.u[j] = cvt2(e0, e1);
        }
        #pragma unroll
        for (int nf = 0; nf < 4; nf++) {
            const int n = nf*16 + l16;
            const bf16x8 bfr = *(const bf16x8*)&Bs[n*256 + 8*((ks*4 + quad) ^ (n & 7))];
            acc[nf] = __builtin_amdgcn_mfma_f32_16x16x32_bf16(a.b, bfr, acc[nf], 0, 0, 0);
        }
    }

    const float g  = 1.f / (1.f + __expf(-gatep[0]));
    const float og = 1.f - g;

    #pragma unroll
    for (int nf = 0; nf < 4; nf++) {
        const int col = n0 + nf*16 + l16;
        #pragma unroll
        for (int r = 0; r < 4; r++) {
            const int row = rowbase + quad*4 + r;
            const float xv  = X [row*DMODEL + col];
            const float pev = PE[row*DMODEL + col];
            Out[row*DMODEL + col] = xv + og * pev + g * acc[nf][r];
        }
    }
}

// ---------------------------------------------------------------------------
extern "C" void kernel_launch(void* const* d_in, const int* in_sizes, int n_in,
                              void* d_out, int out_size, void* d_ws, size_t ws_size,
                              hipStream_t stream)
{
    const float* x    = (const float*)d_in[0];
    const float* pe   = (const float*)d_in[1];
    const float* Wq   = (const float*)d_in[2];
    const float* bq   = (const float*)d_in[3];
    const float* Wk   = (const float*)d_in[4];
    const float* bk   = (const float*)d_in[5];
    const float* Wo   = (const float*)d_in[6];
    const float* bo   = (const float*)d_in[7];
    const float* bt   = (const float*)d_in[8];
    const float* gate = (const float*)d_in[9];
    float* out = (float*)d_out;

    char* w = (char*)d_ws;
    const size_t MB = 1024u*1024u;
    unsigned short* Qb  = (unsigned short*)(w);               // 4 MB
    unsigned short* Kb  = (unsigned short*)(w + 4*MB);        // 4 MB
    unsigned short* Vtb = (unsigned short*)(w + 8*MB);        // 4 MB
    float*          Pb3 = (float*)(w + 12*MB);                // 240 KB (rsvd 256K)
    float*          rsum= (float*)(w + 12*MB + 256u*1024);    // 256 KB
    unsigned short* Op  = (unsigned short*)(w + 13*MB);       // 8 MB (2 halves)

    fused_prep_qk<<<dim3(512), 256, 0, stream>>>(
        x, Wq, bq, Wk, bk, bt, Qb, Kb, Vtb, Pb3);

    attn_mfma<<<dim3(4, 32, 2), 1024, 0, stream>>>(
        Qb, Kb, Vtb, Pb3, Op, rsum);

    gemm_out_mfma<<<dim3(DMODEL/64, NROWS/64), 256, 0, stream>>>(
        Op, rsum, Wo, bo, x, pe, gate, out);
}

// Round 5
// 122.819 us; speedup vs baseline: 1.0333x; 1.0333x over previous
//
#include <hip/hip_runtime.h>
#include <math.h>

// Problem constants (B=8, H=W=32, D=256, heads=4, hd=64)
#define NTOK   1024
#define DMODEL 256
#define NHEADS 4
#define HDIM   64
#define NROWS  8192
#define LOG2E  1.4426950408889634f

typedef __attribute__((ext_vector_type(8))) short          bf16x8;
typedef __attribute__((ext_vector_type(8))) unsigned short ushort8;
typedef __attribute__((ext_vector_type(4))) unsigned short ushort4v;
typedef __attribute__((ext_vector_type(4))) float          f32x4;
typedef __attribute__((ext_vector_type(4))) unsigned int   u32x4;

union ABits { u32x4 u; bf16x8 b; };

__device__ __forceinline__ unsigned short f2bf(float x) {   // RNE fp32->bf16
    unsigned u = __float_as_uint(x);
    u = (u + 0x7fffu + ((u >> 16) & 1u)) >> 16;
    return (unsigned short)u;
}
__device__ __forceinline__ float bf2f(unsigned short u) {
    return __uint_as_float(((unsigned)u) << 16);
}
// pack two fp32 -> two bf16 (truncating) in ONE v_perm_b32 (P values only)
__device__ __forceinline__ unsigned pk_bf2(float lo, float hi) {
    return __builtin_amdgcn_perm(__float_as_uint(hi), __float_as_uint(lo),
                                 0x07060302u);
}
// RNE packed fp32->bf16 pair: 1 instruction for 2 elements (gfx950)
__device__ __forceinline__ unsigned cvt2(float lo, float hi) {
    unsigned r;
    asm("v_cvt_pk_bf16_f32 %0, %1, %2" : "=v"(r) : "v"(lo), "v"(hi));
    return r;
}

// async global->LDS DMA, 16 B per lane; LDS dest = wave-uniform base + lane*16
#define GLD_LDS16(gp, lp)                                            \
    __builtin_amdgcn_global_load_lds(                                \
        (__attribute__((address_space(1))) void*)(gp),               \
        (__attribute__((address_space(3))) void*)(lp), 16, 0, 0)

// ---------------------------------------------------------------------------
// Kernel 1: QK projection GEMM with ALL prep folded into the same 512 blocks.
//  - 64x64 QK tile per block; A cast fp32->bf16 inline (cvt_pk); Wq/Wk tiles
//    reg-staged fp32->bf16 into swizzled LDS.
//  - Each block ALSO transposes the head-h (h = n0/64) slice of its own 64
//    token rows into Vt.  Bias expansion rides on blocks 0..239.
//  Grid 512 = exactly one round at 2 blocks/CU (74 KB LDS).
// ---------------------------------------------------------------------------
__global__ __launch_bounds__(256, 2) void fused_prep_qk(
    const float* __restrict__ X,
    const float* __restrict__ Wq, const float* __restrict__ bq,
    const float* __restrict__ Wk, const float* __restrict__ bk,
    const float* __restrict__ bt,
    unsigned short* __restrict__ Qb, unsigned short* __restrict__ Kb,
    unsigned short* __restrict__ Vt, float* __restrict__ Pb3)
{
    __shared__ unsigned short Bs[2][64 * 256];   // 64 KB weight tiles
    __shared__ unsigned short T[64][80];         // 10 KB V-transpose buffer

    const int bid = blockIdx.x;                  // 0..511
    const int t   = threadIdx.x;
    const int n0  = (bid & 3) * 64;
    const int m0  = (bid >> 2) * 64;
    const int h   = bid & 3;                     // head whose Vt slice we own
    const int b   = bid >> 6;                    // batch of our token rows
    const int kt  = (bid >> 2) & 15;             // 64-token chunk inside batch
    const int bh  = b * NHEADS + h;
    const int wv = t >> 6, lane = t & 63;
    const int quad = lane >> 4, l16 = lane & 15;

    // ---- fused bias expansion (61440 elems across blocks 0..239) ----
    const int gid = bid * 256 + t;
    if (gid < NHEADS * 15 * 1024) {
        const int w2 = gid & 31;
        const int w1 = (gid >> 5) & 31;
        const int rh = (gid >> 10) % 15;
        const int hh = gid / (15 * 1024);
        int rw = w1 - w2 + 7; rw = rw < 0 ? 0 : (rw > 14 ? 14 : rw);
        Pb3[gid] = bt[(rh * 15 + rw) * NHEADS + hh] * LOG2E;
    }

    // ---- stage Wq/Wk 64x256 tiles: fp32 read, cvt_pk cast, swizzled LDS ----
    #pragma unroll
    for (int i = 0; i < 16; i++) {
        const int gran = i * 256 + t;          // 0..4095
        const int mtx  = gran >> 11;           // 0=Wq 1=Wk (uniform per i)
        const int rem  = gran & 2047;
        const int n    = rem >> 5;             // row 0..63
        const int g    = rem & 31;             // K-granule 0..31
        const float* __restrict__ Ws = mtx ? Wk : Wq;
        const float4 f0 = *(const float4*)&Ws[(n0 + n)*DMODEL + g*8];
        const float4 f1 = *(const float4*)&Ws[(n0 + n)*DMODEL + g*8 + 4];
        u32x4 wpk;
        wpk[0] = cvt2(f0.x, f0.y); wpk[1] = cvt2(f0.z, f0.w);
        wpk[2] = cvt2(f1.x, f1.y); wpk[3] = cvt2(f1.z, f1.w);
        *(u32x4*)&Bs[mtx][n*256 + 8*(g ^ (n & 7))] = wpk;
    }

    // ---- V-transpose phase 1: head-h slice of our 64 rows -> T (cast) ----
    {
        const int key = t >> 2;                // 0..63
        const int d4  = (t & 3) * 16;          // 0,16,32,48
        const long roff = (long)(b*NTOK + kt*64 + key)*DMODEL + h*HDIM;
        #pragma unroll
        for (int j = 0; j < 4; j++) {
            const float4 v = *(const float4*)&X[roff + d4 + j*4];
            T[d4+j*4+0][key] = f2bf(v.x); T[d4+j*4+1][key] = f2bf(v.y);
            T[d4+j*4+2][key] = f2bf(v.z); T[d4+j*4+3][key] = f2bf(v.w);
        }
    }
    __syncthreads();

    // ---- V-transpose phase 2: T -> Vt coalesced (overlaps K-loop setup) ----
    #pragma unroll
    for (int i = 0; i < 2; i++) {
        const int tt = t + 256 * i;            // 0..511
        const int d  = tt >> 3;                // 0..63
        const int g  = tt & 7;                 // 0..7
        const ushort8 o = *(const ushort8*)&T[d][g*8];
        *(ushort8*)&Vt[(bh*HDIM + d)*NTOK + kt*64 + g*8] = o;
    }

    // ---- QK GEMM ----
    const int rowbase = m0 + wv * 16;

    f32x4 acc[2][4];
    #pragma unroll
    for (int nf = 0; nf < 4; nf++) {
        const float bvq = bq[n0 + nf*16 + l16];
        const float bvk = bk[n0 + nf*16 + l16];
        acc[0][nf] = (f32x4){bvq,bvq,bvq,bvq};
        acc[1][nf] = (f32x4){bvk,bvk,bvk,bvk};
    }

    const float* __restrict__ Arow = &X[(rowbase + l16) * DMODEL];

    for (int ks = 0; ks < 8; ks++) {
        const float4 x0 = *(const float4*)&Arow[ks*32 + quad*8];
        const float4 x1 = *(const float4*)&Arow[ks*32 + quad*8 + 4];
        ABits a;
        a.u[0] = cvt2(x0.x, x0.y); a.u[1] = cvt2(x0.z, x0.w);
        a.u[2] = cvt2(x1.x, x1.y); a.u[3] = cvt2(x1.z, x1.w);
        #pragma unroll
        for (int nf = 0; nf < 4; nf++) {
            const int n  = nf*16 + l16;
            const int so = n*256 + 8*((ks*4 + quad) ^ (n & 7));
            const bf16x8 bq8 = *(const bf16x8*)&Bs[0][so];
            const bf16x8 bk8 = *(const bf16x8*)&Bs[1][so];
            acc[0][nf] = __builtin_amdgcn_mfma_f32_16x16x32_bf16(a.b, bq8, acc[0][nf], 0, 0, 0);
            acc[1][nf] = __builtin_amdgcn_mfma_f32_16x16x32_bf16(a.b, bk8, acc[1][nf], 0, 0, 0);
        }
    }

    const float qscale = 0.125f * LOG2E;
    #pragma unroll
    for (int nf = 0; nf < 4; nf++) {
        const int col = n0 + nf*16 + l16;
        #pragma unroll
        for (int r = 0; r < 4; r++) {
            const int row = rowbase + quad*4 + r;
            Qb[row*DMODEL + col] = f2bf(acc[0][nf][r] * qscale);
            Kb[row*DMODEL + col] = f2bf(acc[1][nf][r]);
        }
    }
}

// ---------------------------------------------------------------------------
// Kernel 2: MFMA flash attention, split-K=2, 64-key chunks, Q-TILE = 128 rows
// (the best-measured R3 config: 512 threads / 8 waves, 2 blocks/CU so
// barrier stalls are hidden by the co-resident block), PLUS XCD-aware block
// swizzle: the 8 qt-blocks sharing one (bh,qr) K/V working set (128 KB) are
// clustered onto ONE XCD (bijective: 512 % 8 == 0), cutting L3->L2 K/V fill
// ~8x (64 MB -> 8 MB); per-XCD set = 8 pairs x 128 KB = 1 MB << 4 MB L2.
// Grid 512 (1D); LDS 48 KB.  K,V double-buffered async-DMA; Ps XOR-swizzled;
// s_setprio around MFMA clusters.
// ---------------------------------------------------------------------------
__global__ __launch_bounds__(512, 4) void attn_mfma(
    const unsigned short* __restrict__ Qb, const unsigned short* __restrict__ Kb,
    const unsigned short* __restrict__ Vt, const float* __restrict__ Pb3,
    unsigned short* __restrict__ Op, float* __restrict__ rsum)
{
    // XCD swizzle: XCD x (bid%8==x under round-robin dispatch) gets the
    // 64 consecutive sw values x*64..x*64+63 = 8 complete (bh,qr) groups.
    const int bid = blockIdx.x;                   // 0..511
    const int sw  = (bid & 7) * 64 + (bid >> 3);  // bijective remap
    const int qt  = sw & 7;                       // 0..7 (fastest within group)
    const int grp = sw >> 3;                      // 0..63
    const int bh  = grp & 31;                     // 0..31
    const int qr  = grp >> 5;                     // 0..1 (key half)
    const int b    = bh >> 2, h = bh & 3;
    const int t    = threadIdx.x;
    const int wv   = t >> 6, lane = t & 63;   // wv 0..7
    const int quad = lane >> 4, l16 = lane & 15;

    __shared__ unsigned short Ks[2][64 * 64];   // 16 KB
    __shared__ unsigned short Vs[2][64 * 64];   // 16 KB
    __shared__ unsigned short Ps[8][16 * 64];   // 16 KB, XOR-swizzled

    const int qbase = qt * 128 + wv * 16;
    const int h1    = qbase >> 5;               // wave-uniform
    const int w1    = (qbase & 31) + l16;

    bf16x8 qa0, qa1;
    {
        const unsigned short* qp =
            &Qb[(b*NTOK + qbase + l16) * DMODEL + h*HDIM + quad*8];
        qa0 = *(const bf16x8*)(qp);
        qa1 = *(const bf16x8*)(qp + 32);
    }

    f32x4 Of[4] = {};
    float rs = 0.f;

    const unsigned short* KbBase = &Kb[(b*NTOK) * DMODEL + h*HDIM];
    const unsigned short* VtBase = &Vt[(bh*HDIM) * NTOK];
    unsigned short* Pw = Ps[wv];
    const int cbase = qr * 512;

    // async-DMA a 64-key K+V chunk into buffer pb (swizzle via permuted column)
    // 8 waves -> one K granule-row + one V granule-row per wave.
    auto stage = [&](int c0, int pb) {
        {
            const int gr  = wv*64 + lane;           // 0..511
            const int key = gr >> 3, gs = gr & 7;
            const int g   = gs ^ (key & 7);
            GLD_LDS16(&KbBase[(c0 + key)*DMODEL + g*8], &Ks[pb][(wv*64)*8]);
        }
        {
            const int gr = wv*64 + lane;
            const int d  = gr >> 3, gs = gr & 7;
            const int gk = gs ^ (d & 7);
            GLD_LDS16(&VtBase[d*NTOK + c0 + gk*8], &Vs[pb][(wv*64)*8]);
        }
    };

    stage(cbase, 0);
    __syncthreads();          // drains vmcnt -> chunk 0 resident

    for (int ch = 0; ch < 8; ch++) {
        const int c0 = cbase + ch * 64;
        const int p  = ch & 1;

        // async DMA for chunk ch+1 into the back buffer
        if (ch < 7) stage(c0 + 64, p ^ 1);

        // issue the 4 bias loads for this chunk up-front
        f32x4 bias_c[4];
        #pragma unroll
        for (int nt = 0; nt < 4; nt++) {
            const int nk = c0 + nt*16;
            const int h2 = nk >> 5;
            int rh = h1 - h2 + 7; rh = rh < 0 ? 0 : (rh > 14 ? 14 : rh);
            bias_c[nt] = *(const f32x4*)
                &Pb3[(((h*15 + rh)*32) + w1)*32 + (nk & 31) + quad*4];
        }

        // ---- scores: S^T tile = K_tile @ Q^T, bias preloaded in acc ----
        #pragma unroll
        for (int nt = 0; nt < 4; nt++) {
            f32x4 c = bias_c[nt];
            const int kk = nt*16 + l16;
            const bf16x8 ka0 = *(const bf16x8*)&Ks[p][kk*64 + 8*(quad ^ (kk & 7))];
            const bf16x8 ka1 = *(const bf16x8*)&Ks[p][kk*64 + 8*((quad+4) ^ (kk & 7))];
            __builtin_amdgcn_s_setprio(1);
            c = __builtin_amdgcn_mfma_f32_16x16x32_bf16(ka0, qa0, c, 0, 0, 0);
            c = __builtin_amdgcn_mfma_f32_16x16x32_bf16(ka1, qa1, c, 0, 0, 0);
            __builtin_amdgcn_s_setprio(0);
            const float p0 = exp2f(c[0]), p1 = exp2f(c[1]);
            const float p2 = exp2f(c[2]), p3 = exp2f(c[3]);
            rs += (p0 + p1) + (p2 + p3);
            uint2 pk;
            pk.x = pk_bf2(p0, p1);     // truncating bf16 pair-pack (1 instr)
            pk.y = pk_bf2(p2, p3);
            // P store: row=qrow=l16, keys nt*16+quad*4..+3 (swizzled granule)
            const int g = nt*2 + (quad >> 1);
            *(uint2*)&Pw[l16*64 + 8*(g ^ (l16 & 7)) + (quad & 1)*4] = pk;
        }
        // same-wave P write->read: DS pipe is in-order per wave; pin ordering
        __builtin_amdgcn_wave_barrier();

        // ---- PV: O += P V ----
        __builtin_amdgcn_s_setprio(1);
        #pragma unroll
        for (int ks = 0; ks < 2; ks++) {
            const bf16x8 pa = *(const bf16x8*)&Pw[l16*64 + 8*((ks*4 + quad) ^ (l16 & 7))];
            #pragma unroll
            for (int dt = 0; dt < 4; dt++) {
                const int dcol = dt*16 + l16;
                const bf16x8 vb = *(const bf16x8*)
                    &Vs[p][dcol*64 + 8*((ks*4 + quad) ^ (dcol & 7))];
                Of[dt] = __builtin_amdgcn_mfma_f32_16x16x32_bf16(pa, vb, Of[dt], 0, 0, 0);
            }
        }
        __builtin_amdgcn_s_setprio(0);

        // all waves done with buf p; ch+1 DMA drained (vmcnt(0) before barrier)
        if (ch < 7) __syncthreads();
    }

    // ---- epilogue: partial row sums + unnormalized bf16 partial O ----
    float tot = rs;
    tot += __shfl_xor(tot, 16);
    tot += __shfl_xor(tot, 32);          // full half-sum for q-row l16
    if (quad == 0)
        rsum[(qr*32 + bh)*NTOK + qbase + l16] = tot;

    #pragma unroll
    for (int dt = 0; dt < 4; dt++)
        #pragma unroll
        for (int r = 0; r < 4; r++) {
            const int row = qbase + quad*4 + r;
            Op[((long)qr*NROWS + b*NTOK + row)*DMODEL + h*HDIM + dt*16 + l16]
                = f2bf(Of[dt][r]);
        }
}

// ---------------------------------------------------------------------------
// Kernel 3: MFMA output projection + gated blend with FUSED 2-way split-K
// combine: A-frag = (Op0+Op1) * rinv[head] built in-register.
// Wo tile cast fp32->bf16 inline (reg-staged, swizzled LDS) — no Wob buffer.
// out = x + (1-g)*pe + g*(O @ Wo^T + bo), fp32 out.  64x64 tile, 512 blocks.
// ---------------------------------------------------------------------------
__global__ __launch_bounds__(256, 2) void gemm_out_mfma(
    const unsigned short* __restrict__ Op, const float* __restrict__ rsum,
    const float* __restrict__ Wo, const float* __restrict__ bo,
    const float* __restrict__ X, const float* __restrict__ PE,
    const float* __restrict__ gatep,
    float* __restrict__ Out)
{
    const int n0 = blockIdx.x * 64;
    const int m0 = blockIdx.y * 64;
    const int t  = threadIdx.x;
    const int wv = t >> 6, lane = t & 63;
    const int quad = lane >> 4, l16 = lane & 15;

    __shared__ unsigned short Bs[64 * 256];

    #pragma unroll
    for (int i = 0; i < 8; i++) {
        const int gran = i * 256 + t;          // 0..2047
        const int n    = gran >> 5;            // row 0..63
        const int g    = gran & 31;            // K-granule 0..31
        const float4 f0 = *(const float4*)&Wo[(n0 + n)*DMODEL + g*8];
        const float4 f1 = *(const float4*)&Wo[(n0 + n)*DMODEL + g*8 + 4];
        u32x4 wpk;
        wpk[0] = cvt2(f0.x, f0.y); wpk[1] = cvt2(f0.z, f0.w);
        wpk[2] = cvt2(f1.x, f1.y); wpk[3] = cvt2(f1.z, f1.w);
        *(u32x4*)&Bs[n*256 + 8*(g ^ (n & 7))] = wpk;
    }
    __syncthreads();

    const int rowbase = m0 + wv * 16;
    const int arow = rowbase + l16;          // this lane's A row
    const int ab = arow >> 10, an = arow & 1023;

    // per-head 1/(l0+l1) for this row
    float rinv4[4];
    #pragma unroll
    for (int hh = 0; hh < 4; hh++) {
        const float l0 = rsum[(      ab*NHEADS + hh)*NTOK + an];
        const float l1 = rsum[(32 +  ab*NHEADS + hh)*NTOK + an];
        rinv4[hh] = 1.0f / (l0 + l1);
    }

    f32x4 acc[4];
    #pragma unroll
    for (int nf = 0; nf < 4; nf++) {
        const float bv = bo[n0 + nf*16 + l16];
        acc[nf] = (f32x4){bv,bv,bv,bv};
    }

    for (int ks = 0; ks < 8; ks++) {
        const float ri = rinv4[ks >> 1];     // head = (ks*32)/64
        const long aoff = (long)arow*DMODEL + ks*32 + quad*8;
        const ushort8 p0 = *(const ushort8*)&Op[aoff];
        const ushort8 p1 = *(const ushort8*)&Op[(long)NROWS*DMODEL + aoff];
        ABits a;
        #pragma unroll
        for (int j = 0; j < 4; j++) {
            const float e0 = (bf2f(p0[2*j  ]) + bf2f(p1[2*j  ])) * ri;
            const float e1 = (bf2f(p0[2*j+1]) + bf2f(p1[2*j+1])) * ri;
            a.u[j] = cvt2(e0, e1);
        }
        #pragma unroll
        for (int nf = 0; nf < 4; nf++) {
            const int n = nf*16 + l16;
            const bf16x8 bfr = *(const bf16x8*)&Bs[n*256 + 8*((ks*4 + quad) ^ (n & 7))];
            acc[nf] = __builtin_amdgcn_mfma_f32_16x16x32_bf16(a.b, bfr, acc[nf], 0, 0, 0);
        }
    }

    const float g  = 1.f / (1.f + __expf(-gatep[0]));
    const float og = 1.f - g;

    #pragma unroll
    for (int nf = 0; nf < 4; nf++) {
        const int col = n0 + nf*16 + l16;
        #pragma unroll
        for (int r = 0; r < 4; r++) {
            const int row = rowbase + quad*4 + r;
            const float xv  = X [row*DMODEL + col];
            const float pev = PE[row*DMODEL + col];
            Out[row*DMODEL + col] = xv + og * pev + g * acc[nf][r];
        }
    }
}

// ---------------------------------------------------------------------------
extern "C" void kernel_launch(void* const* d_in, const int* in_sizes, int n_in,
                              void* d_out, int out_size, void* d_ws, size_t ws_size,
                              hipStream_t stream)
{
    const float* x    = (const float*)d_in[0];
    const float* pe   = (const float*)d_in[1];
    const float* Wq   = (const float*)d_in[2];
    const float* bq   = (const float*)d_in[3];
    const float* Wk   = (const float*)d_in[4];
    const float* bk   = (const float*)d_in[5];
    const float* Wo   = (const float*)d_in[6];
    const float* bo   = (const float*)d_in[7];
    const float* bt   = (const float*)d_in[8];
    const float* gate = (const float*)d_in[9];
    float* out = (float*)d_out;

    char* w = (char*)d_ws;
    const size_t MB = 1024u*1024u;
    unsigned short* Qb  = (unsigned short*)(w);               // 4 MB
    unsigned short* Kb  = (unsigned short*)(w + 4*MB);        // 4 MB
    unsigned short* Vtb = (unsigned short*)(w + 8*MB);        // 4 MB
    float*          Pb3 = (float*)(w + 12*MB);                // 240 KB (rsvd 256K)
    float*          rsum= (float*)(w + 12*MB + 256u*1024);    // 256 KB
    unsigned short* Op  = (unsigned short*)(w + 13*MB);       // 8 MB (2 halves)

    fused_prep_qk<<<dim3(512), 256, 0, stream>>>(
        x, Wq, bq, Wk, bk, bt, Qb, Kb, Vtb, Pb3);

    attn_mfma<<<dim3(512), 512, 0, stream>>>(
        Qb, Kb, Vtb, Pb3, Op, rsum);

    gemm_out_mfma<<<dim3(DMODEL/64, NROWS/64), 256, 0, stream>>>(
        Op, rsum, Wo, bo, x, pe, gate, out);
}

// Round 6
// 122.272 us; speedup vs baseline: 1.0380x; 1.0045x over previous
//
#include <hip/hip_runtime.h>
#include <math.h>

// Problem constants (B=8, H=W=32, D=256, heads=4, hd=64)
#define NTOK   1024
#define DMODEL 256
#define NHEADS 4
#define HDIM   64
#define NROWS  8192
#define LOG2E  1.4426950408889634f

typedef __attribute__((ext_vector_type(8))) short          bf16x8;
typedef __attribute__((ext_vector_type(8))) unsigned short ushort8;
typedef __attribute__((ext_vector_type(4))) unsigned short ushort4v;
typedef __attribute__((ext_vector_type(4))) float          f32x4;
typedef __attribute__((ext_vector_type(4))) unsigned int   u32x4;

union ABits { u32x4 u; bf16x8 b; };

__device__ __forceinline__ unsigned short f2bf(float x) {   // RNE fp32->bf16
    unsigned u = __float_as_uint(x);
    u = (u + 0x7fffu + ((u >> 16) & 1u)) >> 16;
    return (unsigned short)u;
}
__device__ __forceinline__ float bf2f(unsigned short u) {
    return __uint_as_float(((unsigned)u) << 16);
}
// pack two fp32 -> two bf16 (truncating) in ONE v_perm_b32 (P values only)
__device__ __forceinline__ unsigned pk_bf2(float lo, float hi) {
    return __builtin_amdgcn_perm(__float_as_uint(hi), __float_as_uint(lo),
                                 0x07060302u);
}
// RNE packed fp32->bf16 pair: 1 instruction for 2 elements (gfx950)
__device__ __forceinline__ unsigned cvt2(float lo, float hi) {
    unsigned r;
    asm("v_cvt_pk_bf16_f32 %0, %1, %2" : "=v"(r) : "v"(lo), "v"(hi));
    return r;
}

// async global->LDS DMA, 16 B per lane; LDS dest = wave-uniform base + lane*16
#define GLD_LDS16(gp, lp)                                            \
    __builtin_amdgcn_global_load_lds(                                \
        (__attribute__((address_space(1))) void*)(gp),               \
        (__attribute__((address_space(3))) void*)(lp), 16, 0, 0)

// ---------------------------------------------------------------------------
// Kernel 1: QK projection GEMM with ALL prep folded into the same 512 blocks.
//  (unchanged from R5)
// ---------------------------------------------------------------------------
__global__ __launch_bounds__(256, 2) void fused_prep_qk(
    const float* __restrict__ X,
    const float* __restrict__ Wq, const float* __restrict__ bq,
    const float* __restrict__ Wk, const float* __restrict__ bk,
    const float* __restrict__ bt,
    unsigned short* __restrict__ Qb, unsigned short* __restrict__ Kb,
    unsigned short* __restrict__ Vt, float* __restrict__ Pb3)
{
    __shared__ unsigned short Bs[2][64 * 256];   // 64 KB weight tiles
    __shared__ unsigned short T[64][80];         // 10 KB V-transpose buffer

    const int bid = blockIdx.x;                  // 0..511
    const int t   = threadIdx.x;
    const int n0  = (bid & 3) * 64;
    const int m0  = (bid >> 2) * 64;
    const int h   = bid & 3;                     // head whose Vt slice we own
    const int b   = bid >> 6;                    // batch of our token rows
    const int kt  = (bid >> 2) & 15;             // 64-token chunk inside batch
    const int bh  = b * NHEADS + h;
    const int wv = t >> 6, lane = t & 63;
    const int quad = lane >> 4, l16 = lane & 15;

    // ---- fused bias expansion (61440 elems across blocks 0..239) ----
    const int gid = bid * 256 + t;
    if (gid < NHEADS * 15 * 1024) {
        const int w2 = gid & 31;
        const int w1 = (gid >> 5) & 31;
        const int rh = (gid >> 10) % 15;
        const int hh = gid / (15 * 1024);
        int rw = w1 - w2 + 7; rw = rw < 0 ? 0 : (rw > 14 ? 14 : rw);
        Pb3[gid] = bt[(rh * 15 + rw) * NHEADS + hh] * LOG2E;
    }

    // ---- stage Wq/Wk 64x256 tiles: fp32 read, cvt_pk cast, swizzled LDS ----
    #pragma unroll
    for (int i = 0; i < 16; i++) {
        const int gran = i * 256 + t;          // 0..4095
        const int mtx  = gran >> 11;           // 0=Wq 1=Wk (uniform per i)
        const int rem  = gran & 2047;
        const int n    = rem >> 5;             // row 0..63
        const int g    = rem & 31;             // K-granule 0..31
        const float* __restrict__ Ws = mtx ? Wk : Wq;
        const float4 f0 = *(const float4*)&Ws[(n0 + n)*DMODEL + g*8];
        const float4 f1 = *(const float4*)&Ws[(n0 + n)*DMODEL + g*8 + 4];
        u32x4 wpk;
        wpk[0] = cvt2(f0.x, f0.y); wpk[1] = cvt2(f0.z, f0.w);
        wpk[2] = cvt2(f1.x, f1.y); wpk[3] = cvt2(f1.z, f1.w);
        *(u32x4*)&Bs[mtx][n*256 + 8*(g ^ (n & 7))] = wpk;
    }

    // ---- V-transpose phase 1: head-h slice of our 64 rows -> T (cast) ----
    {
        const int key = t >> 2;                // 0..63
        const int d4  = (t & 3) * 16;          // 0,16,32,48
        const long roff = (long)(b*NTOK + kt*64 + key)*DMODEL + h*HDIM;
        #pragma unroll
        for (int j = 0; j < 4; j++) {
            const float4 v = *(const float4*)&X[roff + d4 + j*4];
            T[d4+j*4+0][key] = f2bf(v.x); T[d4+j*4+1][key] = f2bf(v.y);
            T[d4+j*4+2][key] = f2bf(v.z); T[d4+j*4+3][key] = f2bf(v.w);
        }
    }
    __syncthreads();

    // ---- V-transpose phase 2: T -> Vt coalesced (overlaps K-loop setup) ----
    #pragma unroll
    for (int i = 0; i < 2; i++) {
        const int tt = t + 256 * i;            // 0..511
        const int d  = tt >> 3;                // 0..63
        const int g  = tt & 7;                 // 0..7
        const ushort8 o = *(const ushort8*)&T[d][g*8];
        *(ushort8*)&Vt[(bh*HDIM + d)*NTOK + kt*64 + g*8] = o;
    }

    // ---- QK GEMM ----
    const int rowbase = m0 + wv * 16;

    f32x4 acc[2][4];
    #pragma unroll
    for (int nf = 0; nf < 4; nf++) {
        const float bvq = bq[n0 + nf*16 + l16];
        const float bvk = bk[n0 + nf*16 + l16];
        acc[0][nf] = (f32x4){bvq,bvq,bvq,bvq};
        acc[1][nf] = (f32x4){bvk,bvk,bvk,bvk};
    }

    const float* __restrict__ Arow = &X[(rowbase + l16) * DMODEL];

    for (int ks = 0; ks < 8; ks++) {
        const float4 x0 = *(const float4*)&Arow[ks*32 + quad*8];
        const float4 x1 = *(const float4*)&Arow[ks*32 + quad*8 + 4];
        ABits a;
        a.u[0] = cvt2(x0.x, x0.y); a.u[1] = cvt2(x0.z, x0.w);
        a.u[2] = cvt2(x1.x, x1.y); a.u[3] = cvt2(x1.z, x1.w);
        #pragma unroll
        for (int nf = 0; nf < 4; nf++) {
            const int n  = nf*16 + l16;
            const int so = n*256 + 8*((ks*4 + quad) ^ (n & 7));
            const bf16x8 bq8 = *(const bf16x8*)&Bs[0][so];
            const bf16x8 bk8 = *(const bf16x8*)&Bs[1][so];
            acc[0][nf] = __builtin_amdgcn_mfma_f32_16x16x32_bf16(a.b, bq8, acc[0][nf], 0, 0, 0);
            acc[1][nf] = __builtin_amdgcn_mfma_f32_16x16x32_bf16(a.b, bk8, acc[1][nf], 0, 0, 0);
        }
    }

    const float qscale = 0.125f * LOG2E;
    #pragma unroll
    for (int nf = 0; nf < 4; nf++) {
        const int col = n0 + nf*16 + l16;
        #pragma unroll
        for (int r = 0; r < 4; r++) {
            const int row = rowbase + quad*4 + r;
            Qb[row*DMODEL + col] = f2bf(acc[0][nf][r] * qscale);
            Kb[row*DMODEL + col] = f2bf(acc[1][nf][r]);
        }
    }
}

// ---------------------------------------------------------------------------
// Kernel 2: MFMA flash attention, split-K=2, 64-key chunks, Q-TILE = 128 rows,
// 512 thr / 8 waves, 2 blocks/CU — R3/R5 config — NOW with the T3+T4 pipeline:
// TRIPLE-buffered K/V (prefetch depth 2) + counted `s_waitcnt vmcnt(2)` + RAW
// s_barrier, so prefetch loads stay in flight ACROSS barriers (never drain to
// 0 in the main loop).  Guards: bias loads issued before the stage (+"memory"
// fence) so the compiler's bias wait can't drain the pipeline (vmcnt retires
// in order); sched_barrier(0) after each raw barrier (rule 18); Ps is
// per-wave so no lgkmcnt needed at block barriers.  LDS 24+24+16 = 64 KB.
// XCD-aware bijective block swizzle kept from R5.
// ---------------------------------------------------------------------------
__global__ __launch_bounds__(512, 4) void attn_mfma(
    const unsigned short* __restrict__ Qb, const unsigned short* __restrict__ Kb,
    const unsigned short* __restrict__ Vt, const float* __restrict__ Pb3,
    unsigned short* __restrict__ Op, float* __restrict__ rsum)
{
    const int bid = blockIdx.x;                   // 0..511
    const int sw  = (bid & 7) * 64 + (bid >> 3);  // bijective XCD remap
    const int qt  = sw & 7;                       // 0..7
    const int grp = sw >> 3;                      // 0..63
    const int bh  = grp & 31;                     // 0..31
    const int qr  = grp >> 5;                     // 0..1 (key half)
    const int b    = bh >> 2, h = bh & 3;
    const int t    = threadIdx.x;
    const int wv   = t >> 6, lane = t & 63;   // wv 0..7
    const int quad = lane >> 4, l16 = lane & 15;

    __shared__ unsigned short Ks[3][64 * 64];   // 24 KB (triple buffer)
    __shared__ unsigned short Vs[3][64 * 64];   // 24 KB
    __shared__ unsigned short Ps[8][16 * 64];   // 16 KB, XOR-swizzled

    const int qbase = qt * 128 + wv * 16;
    const int h1    = qbase >> 5;               // wave-uniform
    const int w1    = (qbase & 31) + l16;

    bf16x8 qa0, qa1;
    {
        const unsigned short* qp =
            &Qb[(b*NTOK + qbase + l16) * DMODEL + h*HDIM + quad*8];
        qa0 = *(const bf16x8*)(qp);
        qa1 = *(const bf16x8*)(qp + 32);
    }

    f32x4 Of[4] = {};
    float rs = 0.f;

    const unsigned short* KbBase = &Kb[(b*NTOK) * DMODEL + h*HDIM];
    const unsigned short* VtBase = &Vt[(bh*HDIM) * NTOK];
    unsigned short* Pw = Ps[wv];
    const int cbase = qr * 512;

    // async-DMA a 64-key K+V chunk into buffer pb (swizzle via permuted column)
    // 8 waves -> one K granule-row + one V granule-row per wave (2 vmcnt/wave).
    auto stage = [&](int c0, int pb) {
        {
            const int gr  = wv*64 + lane;           // 0..511
            const int key = gr >> 3, gs = gr & 7;
            const int g   = gs ^ (key & 7);
            GLD_LDS16(&KbBase[(c0 + key)*DMODEL + g*8], &Ks[pb][(wv*64)*8]);
        }
        {
            const int gr = wv*64 + lane;
            const int d  = gr >> 3, gs = gr & 7;
            const int gk = gs ^ (d & 7);
            GLD_LDS16(&VtBase[d*NTOK + c0 + gk*8], &Vs[pb][(wv*64)*8]);
        }
    };

    // prologue: prefetch chunks 0 and 1; wait only for chunk 0 (vmcnt(2))
    stage(cbase,      0);
    stage(cbase + 64, 1);
    asm volatile("s_waitcnt vmcnt(2)" ::: "memory");
    __builtin_amdgcn_s_barrier();
    __builtin_amdgcn_sched_barrier(0);

    #pragma unroll
    for (int ch = 0; ch < 8; ch++) {
        const int c0 = cbase + ch * 64;
        const int p  = ch % 3;                  // compile-time (full unroll)

        // bias loads FIRST (older than stage loads -> compiler's wait for
        // bias retires stage(ch+1) at most, never the fresh stage(ch+2))
        f32x4 bias_c[4];
        #pragma unroll
        for (int nt = 0; nt < 4; nt++) {
            const int nk = c0 + nt*16;
            const int h2 = nk >> 5;
            int rh = h1 - h2 + 7; rh = rh < 0 ? 0 : (rh > 14 ? 14 : rh);
            bias_c[nt] = *(const f32x4*)
                &Pb3[(((h*15 + rh)*32) + w1)*32 + (nk & 31) + quad*4];
        }
        asm volatile("" ::: "memory");          // pin bias-before-stage order

        // prefetch chunk ch+2 (depth-2 pipeline)
        if (ch < 6) stage(c0 + 128, (ch + 2) % 3);

        // ---- scores: S^T tile = K_tile @ Q^T, bias preloaded in acc ----
        #pragma unroll
        for (int nt = 0; nt < 4; nt++) {
            f32x4 c = bias_c[nt];
            const int kk = nt*16 + l16;
            const bf16x8 ka0 = *(const bf16x8*)&Ks[p][kk*64 + 8*(quad ^ (kk & 7))];
            const bf16x8 ka1 = *(const bf16x8*)&Ks[p][kk*64 + 8*((quad+4) ^ (kk & 7))];
            __builtin_amdgcn_s_setprio(1);
            c = __builtin_amdgcn_mfma_f32_16x16x32_bf16(ka0, qa0, c, 0, 0, 0);
            c = __builtin_amdgcn_mfma_f32_16x16x32_bf16(ka1, qa1, c, 0, 0, 0);
            __builtin_amdgcn_s_setprio(0);
            const float p0 = exp2f(c[0]), p1 = exp2f(c[1]);
            const float p2 = exp2f(c[2]), p3 = exp2f(c[3]);
            rs += (p0 + p1) + (p2 + p3);
            uint2 pk;
            pk.x = pk_bf2(p0, p1);     // truncating bf16 pair-pack (1 instr)
            pk.y = pk_bf2(p2, p3);
            // P store: row=qrow=l16, keys nt*16+quad*4..+3 (swizzled granule)
            const int g = nt*2 + (quad >> 1);
            *(uint2*)&Pw[l16*64 + 8*(g ^ (l16 & 7)) + (quad & 1)*4] = pk;
        }
        // same-wave P write->read: DS pipe is in-order per wave; pin ordering
        __builtin_amdgcn_wave_barrier();

        // ---- PV: O += P V ----
        __builtin_amdgcn_s_setprio(1);
        #pragma unroll
        for (int ks = 0; ks < 2; ks++) {
            const bf16x8 pa = *(const bf16x8*)&Pw[l16*64 + 8*((ks*4 + quad) ^ (l16 & 7))];
            #pragma unroll
            for (int dt = 0; dt < 4; dt++) {
                const int dcol = dt*16 + l16;
                const bf16x8 vb = *(const bf16x8*)
                    &Vs[p][dcol*64 + 8*((ks*4 + quad) ^ (dcol & 7))];
                Of[dt] = __builtin_amdgcn_mfma_f32_16x16x32_bf16(pa, vb, Of[dt], 0, 0, 0);
            }
        }
        __builtin_amdgcn_s_setprio(0);

        // counted-vmcnt barrier: guarantee chunk ch+1 resident for ALL waves;
        // chunk ch+2's loads stay in flight across the barrier (never drain).
        if (ch < 7) {
            if (ch < 6) asm volatile("s_waitcnt vmcnt(2)" ::: "memory");
            else        asm volatile("s_waitcnt vmcnt(0)" ::: "memory");
            __builtin_amdgcn_s_barrier();
            __builtin_amdgcn_sched_barrier(0);
        }
    }

    // ---- epilogue: partial row sums + unnormalized bf16 partial O ----
    float tot = rs;
    tot += __shfl_xor(tot, 16);
    tot += __shfl_xor(tot, 32);          // full half-sum for q-row l16
    if (quad == 0)
        rsum[(qr*32 + bh)*NTOK + qbase + l16] = tot;

    #pragma unroll
    for (int dt = 0; dt < 4; dt++)
        #pragma unroll
        for (int r = 0; r < 4; r++) {
            const int row = qbase + quad*4 + r;
            Op[((long)qr*NROWS + b*NTOK + row)*DMODEL + h*HDIM + dt*16 + l16]
                = f2bf(Of[dt][r]);
        }
}

// ---------------------------------------------------------------------------
// Kernel 3: MFMA output projection + gated blend with FUSED 2-way split-K
// combine (unchanged from R5).
// ---------------------------------------------------------------------------
__global__ __launch_bounds__(256, 2) void gemm_out_mfma(
    const unsigned short* __restrict__ Op, const float* __restrict__ rsum,
    const float* __restrict__ Wo, const float* __restrict__ bo,
    const float* __restrict__ X, const float* __restrict__ PE,
    const float* __restrict__ gatep,
    float* __restrict__ Out)
{
    const int n0 = blockIdx.x * 64;
    const int m0 = blockIdx.y * 64;
    const int t  = threadIdx.x;
    const int wv = t >> 6, lane = t & 63;
    const int quad = lane >> 4, l16 = lane & 15;

    __shared__ unsigned short Bs[64 * 256];

    #pragma unroll
    for (int i = 0; i < 8; i++) {
        const int gran = i * 256 + t;          // 0..2047
        const int n    = gran >> 5;            // row 0..63
        const int g    = gran & 31;            // K-granule 0..31
        const float4 f0 = *(const float4*)&Wo[(n0 + n)*DMODEL + g*8];
        const float4 f1 = *(const float4*)&Wo[(n0 + n)*DMODEL + g*8 + 4];
        u32x4 wpk;
        wpk[0] = cvt2(f0.x, f0.y); wpk[1] = cvt2(f0.z, f0.w);
        wpk[2] = cvt2(f1.x, f1.y); wpk[3] = cvt2(f1.z, f1.w);
        *(u32x4*)&Bs[n*256 + 8*(g ^ (n & 7))] = wpk;
    }
    __syncthreads();

    const int rowbase = m0 + wv * 16;
    const int arow = rowbase + l16;          // this lane's A row
    const int ab = arow >> 10, an = arow & 1023;

    // per-head 1/(l0+l1) for this row
    float rinv4[4];
    #pragma unroll
    for (int hh = 0; hh < 4; hh++) {
        const float l0 = rsum[(      ab*NHEADS + hh)*NTOK + an];
        const float l1 = rsum[(32 +  ab*NHEADS + hh)*NTOK + an];
        rinv4[hh] = 1.0f / (l0 + l1);
    }

    f32x4 acc[4];
    #pragma unroll
    for (int nf = 0; nf < 4; nf++) {
        const float bv = bo[n0 + nf*16 + l16];
        acc[nf] = (f32x4){bv,bv,bv,bv};
    }

    for (int ks = 0; ks < 8; ks++) {
        const float ri = rinv4[ks >> 1];     // head = (ks*32)/64
        const long aoff = (long)arow*DMODEL + ks*32 + quad*8;
        const ushort8 p0 = *(const ushort8*)&Op[aoff];
        const ushort8 p1 = *(const ushort8*)&Op[(long)NROWS*DMODEL + aoff];
        ABits a;
        #pragma unroll
        for (int j = 0; j < 4; j++) {
            const float e0 = (bf2f(p0[2*j  ]) + bf2f(p1[2*j  ])) * ri;
            const float e1 = (bf2f(p0[2*j+1]) + bf2f(p1[2*j+1])) * ri;
            a.u[j] = cvt2(e0, e1);
        }
        #pragma unroll
        for (int nf = 0; nf < 4; nf++) {
            const int n = nf*16 + l16;
            const bf16x8 bfr = *(const bf16x8*)&Bs[n*256 + 8*((ks*4 + quad) ^ (n & 7))];
            acc[nf] = __builtin_amdgcn_mfma_f32_16x16x32_bf16(a.b, bfr, acc[nf], 0, 0, 0);
        }
    }

    const float g  = 1.f / (1.f + __expf(-gatep[0]));
    const float og = 1.f - g;

    #pragma unroll
    for (int nf = 0; nf < 4; nf++) {
        const int col = n0 + nf*16 + l16;
        #pragma unroll
        for (int r = 0; r < 4; r++) {
            const int row = rowbase + quad*4 + r;
            const float xv  = X [row*DMODEL + col];
            const float pev = PE[row*DMODEL + col];
            Out[row*DMODEL + col] = xv + og * pev + g * acc[nf][r];
        }
    }
}

// ---------------------------------------------------------------------------
extern "C" void kernel_launch(void* const* d_in, const int* in_sizes, int n_in,
                              void* d_out, int out_size, void* d_ws, size_t ws_size,
                              hipStream_t stream)
{
    const float* x    = (const float*)d_in[0];
    const float* pe   = (const float*)d_in[1];
    const float* Wq   = (const float*)d_in[2];
    const float* bq   = (const float*)d_in[3];
    const float* Wk   = (const float*)d_in[4];
    const float* bk   = (const float*)d_in[5];
    const float* Wo   = (const float*)d_in[6];
    const float* bo   = (const float*)d_in[7];
    const float* bt   = (const float*)d_in[8];
    const float* gate = (const float*)d_in[9];
    float* out = (float*)d_out;

    char* w = (char*)d_ws;
    const size_t MB = 1024u*1024u;
    unsigned short* Qb  = (unsigned short*)(w);               // 4 MB
    unsigned short* Kb  = (unsigned short*)(w + 4*MB);        // 4 MB
    unsigned short* Vtb = (unsigned short*)(w + 8*MB);        // 4 MB
    float*          Pb3 = (float*)(w + 12*MB);                // 240 KB (rsvd 256K)
    float*          rsum= (float*)(w + 12*MB + 256u*1024);    // 256 KB
    unsigned short* Op  = (unsigned short*)(w + 13*MB);       // 8 MB (2 halves)

    fused_prep_qk<<<dim3(512), 256, 0, stream>>>(
        x, Wq, bq, Wk, bk, bt, Qb, Kb, Vtb, Pb3);

    attn_mfma<<<dim3(512), 512, 0, stream>>>(
        Qb, Kb, Vtb, Pb3, Op, rsum);

    gemm_out_mfma<<<dim3(DMODEL/64, NROWS/64), 256, 0, stream>>>(
        Op, rsum, Wo, bo, x, pe, gate, out);
}